// Round 5
// baseline (278.856 us; speedup 1.0000x reference)
//
#include <hip/hip_runtime.h>

typedef __attribute__((ext_vector_type(8))) short short8;
typedef __attribute__((ext_vector_type(4))) float f32x4;
typedef __attribute__((ext_vector_type(4))) unsigned short u16x4;

#define MFMA_BF16(a, b, c) __builtin_amdgcn_mfma_f32_16x16x32_bf16((a), (b), (c), 0, 0, 0)

__device__ __forceinline__ unsigned short f2bf(float f) {
  unsigned int u = __builtin_bit_cast(unsigned int, f);
  u += 0x7fffu + ((u >> 16) & 1u);
  return (unsigned short)(u >> 16);
}

// async global->LDS, 16 bytes per lane; LDS dest = wave-uniform base + lane*16
__device__ __forceinline__ void gload_lds16(const void* g, void* lds) {
  __builtin_amdgcn_global_load_lds(
      (const __attribute__((address_space(1))) unsigned int*)g,
      (__attribute__((address_space(3))) unsigned int*)lds, 16, 0, 0);
}

// ---------------- cast f32 -> bf16 (vectorized) ----------------
__global__ __launch_bounds__(256) void cast_f32_bf16(const float* __restrict__ src,
                                                     unsigned short* __restrict__ dst, int n4) {
  int i = blockIdx.x * 256 + threadIdx.x;
  if (i >= n4) return;
  float4 v = ((const float4*)src)[i];
  u16x4 r = { f2bf(v.x), f2bf(v.y), f2bf(v.z), f2bf(v.w) };
  ((u16x4*)dst)[i] = r;
}

// ---------------- GEMM (m97 structure): C[M,N] = A[M,K] * W[N,K]^T + bias ----------------
template <int EPI>
__global__ __launch_bounds__(256) void gemm_lds(const unsigned short* __restrict__ A,
                                                const unsigned short* __restrict__ W,
                                                const float* __restrict__ bias,
                                                void* __restrict__ Cout,
                                                int M, int N, int K) {
  __shared__ unsigned short At[128 * 32];
  __shared__ unsigned short Bt[128 * 32];

  const int tid = threadIdx.x;
  const int w = tid >> 6, l = tid & 63;
  const int lr = l & 15, lq = l >> 4;
  const int wr = w >> 1, wc = w & 1;
  const int row0 = blockIdx.x * 128;
  const int col0 = blockIdx.y * 128;

  const int srow = l >> 2;
  const int skoff = (l & 3) * 8;

  f32x4 acc[4][4] = {};

  const unsigned short* Abase = A + (row0 + srow) * (size_t)K + skoff;
  const unsigned short* Bbase = W + (col0 + srow) * (size_t)K + skoff;

  for (int kt = 0; kt < K; kt += 32) {
#pragma unroll
    for (int j = 0; j < 2; j++) {
      const int c = w * 2 + j;
      gload_lds16(Abase + (size_t)(c * 16) * K + kt, &At[c * 512]);
      gload_lds16(Bbase + (size_t)(c * 16) * K + kt, &Bt[c * 512]);
    }
    __syncthreads();

    short8 af[4], bfr[4];
#pragma unroll
    for (int m = 0; m < 4; m++)
      af[m] = *(const short8*)&At[(wr * 64 + m * 16 + lr) * 32 + lq * 8];
#pragma unroll
    for (int n = 0; n < 4; n++)
      bfr[n] = *(const short8*)&Bt[(wc * 64 + n * 16 + lr) * 32 + lq * 8];
#pragma unroll
    for (int m = 0; m < 4; m++)
#pragma unroll
      for (int n = 0; n < 4; n++)
        acc[m][n] = MFMA_BF16(af[m], bfr[n], acc[m][n]);
    __syncthreads();
  }

#pragma unroll
  for (int n = 0; n < 4; n++) {
    const int col = col0 + wc * 64 + n * 16 + lr;
    const float bv = bias[col];
#pragma unroll
    for (int m = 0; m < 4; m++) {
      const int row = row0 + wr * 64 + m * 16 + lq * 4;
#pragma unroll
      for (int r = 0; r < 4; r++) {
        float v = acc[m][n][r] + bv;
        if (EPI == 0) {
          ((unsigned short*)Cout)[(size_t)(row + r) * N + col] = f2bf(v);
        } else if (EPI == 1) {
          ((float*)Cout)[(size_t)(row + r) * N + col] = v;
        } else {
          float g = 0.5f * v * (1.0f + erff(v * 0.70710678118654752f));
          ((float*)Cout)[(size_t)(row + r) * N + col] = g;
        }
      }
    }
  }
}

// ---------------- maskadd (log2 domain): ma[b][k] = mask ? 0 : -1e10*log2e ----------------
__global__ __launch_bounds__(256) void maskadd_kernel(const int* __restrict__ mask,
                                                      float* __restrict__ ma) {
  int i = blockIdx.x * 256 + threadIdx.x;
  if (i < 4096) ma[i] = (mask[i] == 0) ? -1.4426950408889634e10f : 0.0f;
}

// ---------------- V transpose: VT[(bh*64+d)][k] <- v-slab of qkv ----------------
__global__ __launch_bounds__(256) void vtrans_kernel(const unsigned short* __restrict__ qkv,
                                                     unsigned short* __restrict__ VT) {
  const int bh = blockIdx.x;   // 64
  const int kt = blockIdx.y;   // 16 tiles of 64 keys
  const int t = threadIdx.x;
  const int d = t & 63, kg = t >> 6;
  const unsigned short* basev =
      qkv + ((size_t)(bh >> 4) * 1024 + (bh & 15) * 64) * 3072 + 2048;
  const unsigned short* src = basev + (size_t)(kt * 4 + kg) * 3072 + d;
  unsigned short vals[16];
#pragma unroll
  for (int j = 0; j < 16; j++) vals[j] = src[j * 64];
  short8 v0, v1;
#pragma unroll
  for (int j = 0; j < 8; j++) { v0[j] = (short)vals[j]; v1[j] = (short)vals[8 + j]; }
  size_t dst = ((size_t)bh * 64 + d) * 1024 + kt * 64 + kg * 16;
  *(short8*)&VT[dst] = v0;
  *(short8*)&VT[dst + 8] = v1;
}

// ---------------- flash attention v3b ----------------
// 16 q-rows per wave, swapped QK^T (S^T via mfma(K,Q)), exp2 domain,
// UNCONDITIONAL rescale (attn2-proven math), f2bf packing, mask row in LDS.
struct KV {
  short8 kf[2][2];   // [key-half][d-chunk]
  short8 vf[4];      // V^T frags per d-tile
};

__device__ __forceinline__ void load_kv(KV& f, int kt,
                                        const unsigned short* __restrict__ basek,
                                        const unsigned short* __restrict__ vtb,
                                        int lr, int lq) {
#pragma unroll
  for (int t = 0; t < 2; t++) {
    const unsigned short* ka = basek + (size_t)(kt * 2 + t) * 3072 + lr * 64;
    f.kf[t][0] = *(const short8*)(ka + lq * 8);
    f.kf[t][1] = *(const short8*)(ka + 32 + lq * 8);
  }
#pragma unroll
  for (int n = 0; n < 4; n++)
    f.vf[n] = *(const short8*)(vtb + (size_t)(n * 16 + lr) * 1024 + kt * 32 + lq * 8);
}

__global__ __launch_bounds__(256, 4) void attn3_kernel(const unsigned short* __restrict__ qkv,
                                                       const unsigned short* __restrict__ VT,
                                                       const float* __restrict__ maskadd,
                                                       unsigned short* __restrict__ att) {
  __shared__ float ma_lds[1024];
  __shared__ unsigned short Pl[4][16 * 40];

  const int bh = blockIdx.x, b = bh >> 4, h = bh & 15;
  const int qb = blockIdx.y;  // 0..15
  const int tid = threadIdx.x, w = tid >> 6, l = tid & 63;
  const int lr = l & 15, lq = l >> 4;

  const unsigned short* baseq = qkv + ((size_t)b * 1024 + h * 64) * 3072;
  const unsigned short* basek = baseq + 1024;
  const unsigned short* vtb = VT + (size_t)bh * 64 * 1024;

  // stage mask row (log2-scaled) into LDS once
  ((float4*)ma_lds)[tid] = ((const float4*)(maskadd + b * 1024))[tid];
  __syncthreads();

  // Q fragments: q = qb*64 + w*16 + lr, resident all kernel
  short8 qf[2];
  {
    const int p = qb * 64 + w * 16 + lr;
    const unsigned short* qa = baseq + (p >> 4) * 3072 + (p & 15) * 64;
    qf[0] = *(const short8*)(qa + lq * 8);
    qf[1] = *(const short8*)(qa + 32 + lq * 8);
  }

  float m = -1e30f, ll = 0.f;
  f32x4 o[4] = {};
  unsigned short* pw = &Pl[w][0];
  constexpr float SC = 0.18033688011112042f;  // 0.125 * log2(e)

  KV fa, fb;
  load_kv(fa, 0, basek, vtb, lr, lq);

#pragma unroll 1
  for (int kt = 0; kt < 32; kt += 2) {
    load_kv(fb, (kt + 1) & 31, basek, vtb, lr, lq);

#pragma unroll
    for (int half = 0; half < 2; half++) {
      const KV& f = half ? fb : fa;
      const int kcur = kt + half;

      // S^T = K·Q^T : rows = keys (lq*4+r [+16]), cols = q (lr)
      f32x4 s0 = {0.f, 0.f, 0.f, 0.f}, s1 = {0.f, 0.f, 0.f, 0.f};
      s0 = MFMA_BF16(f.kf[0][0], qf[0], s0);
      s0 = MFMA_BF16(f.kf[0][1], qf[1], s0);
      s1 = MFMA_BF16(f.kf[1][0], qf[0], s1);
      s1 = MFMA_BF16(f.kf[1][1], qf[1], s1);

      const float4 mk0 = *(const float4*)&ma_lds[kcur * 32 + lq * 4];
      const float4 mk1 = *(const float4*)&ma_lds[kcur * 32 + 16 + lq * 4];
      float sv[8];
#pragma unroll
      for (int r = 0; r < 4; r++) {
        sv[r]     = s0[r] * SC + ((const float*)&mk0)[r];
        sv[4 + r] = s1[r] * SC + ((const float*)&mk1)[r];
      }

      // wave-wide max for this lane's q (replicated across lq groups)
      float pm = fmaxf(fmaxf(fmaxf(sv[0], sv[1]), fmaxf(sv[2], sv[3])),
                       fmaxf(fmaxf(sv[4], sv[5]), fmaxf(sv[6], sv[7])));
      pm = fmaxf(pm, __shfl_xor(pm, 16));
      pm = fmaxf(pm, __shfl_xor(pm, 32));

      // unconditional online-softmax rescale (attn2-proven)
      const float mn = fmaxf(m, pm);
      const float sc = __builtin_amdgcn_exp2f(m - mn);
      m = mn;

      float p[8], rs = 0.f;
#pragma unroll
      for (int i = 0; i < 8; i++) { p[i] = __builtin_amdgcn_exp2f(sv[i] - m); rs += p[i]; }
      rs += __shfl_xor(rs, 16);
      rs += __shfl_xor(rs, 32);
      ll = ll * sc + rs;

      // pack P to bf16 (scalar cast), exchange through per-wave LDS: P[q=lr][k_local]
      uint2 wa, wb;
      wa.x = (unsigned)f2bf(p[0]) | ((unsigned)f2bf(p[1]) << 16);
      wa.y = (unsigned)f2bf(p[2]) | ((unsigned)f2bf(p[3]) << 16);
      wb.x = (unsigned)f2bf(p[4]) | ((unsigned)f2bf(p[5]) << 16);
      wb.y = (unsigned)f2bf(p[6]) | ((unsigned)f2bf(p[7]) << 16);
      *(uint2*)&pw[lr * 40 + lq * 4] = wa;
      *(uint2*)&pw[lr * 40 + 16 + lq * 4] = wb;

      // rescale O (O rows q = lq*4+r use sc of lane lq*4+r)
      float scr[4];
#pragma unroll
      for (int r = 0; r < 4; r++) scr[r] = __shfl(sc, lq * 4 + r);
#pragma unroll
      for (int n = 0; n < 4; n++)
#pragma unroll
        for (int r = 0; r < 4; r++) o[n][r] *= scr[r];

      asm volatile("s_waitcnt lgkmcnt(0)" ::: "memory");

      // PV: A = P[q=lr][k=lq*8..+7], B = V^T frags -> O[q][d]
      const short8 pa = *(const short8*)&pw[lr * 40 + lq * 8];
#pragma unroll
      for (int n = 0; n < 4; n++)
        o[n] = MFMA_BF16(pa, f.vf[n], o[n]);
    }

    load_kv(fa, (kt + 2) & 31, basek, vtb, lr, lq);
  }

  // epilogue: normalize, write att[b, q, h*64 + d]
  float inv[4];
#pragma unroll
  for (int r = 0; r < 4; r++) inv[r] = 1.0f / __shfl(ll, lq * 4 + r);
#pragma unroll
  for (int r = 0; r < 4; r++) {
    const int q = qb * 64 + w * 16 + lq * 4 + r;
    const size_t obase = ((size_t)b * 1024 + q) * 1024 + h * 64;
#pragma unroll
    for (int n = 0; n < 4; n++)
      att[obase + n * 16 + lr] = f2bf(o[n][r] * inv[r]);
  }
}

// ---------------- LayerNorm kernels (fp32, E=1024, one row per block) ----------------
__global__ __launch_bounds__(256) void ln1_kernel(const float* __restrict__ x,
                                                  const float* __restrict__ attp,
                                                  const float* __restrict__ g,
                                                  const float* __restrict__ bt,
                                                  float* __restrict__ sf,
                                                  unsigned short* __restrict__ sb) {
  const int row = blockIdx.x, tid = threadIdx.x;
  float4 xv = ((const float4*)(x + row * 1024))[tid];
  float4 av = ((const float4*)(attp + row * 1024))[tid];
  float4 v = {xv.x + av.x, xv.y + av.y, xv.z + av.z, xv.w + av.w};
  float s = v.x + v.y + v.z + v.w;
  float sq = v.x * v.x + v.y * v.y + v.z * v.z + v.w * v.w;
#pragma unroll
  for (int off = 1; off < 64; off <<= 1) { s += __shfl_xor(s, off); sq += __shfl_xor(sq, off); }
  __shared__ float ws[8];
  int wv = tid >> 6, l = tid & 63;
  if (l == 0) { ws[wv] = s; ws[4 + wv] = sq; }
  __syncthreads();
  s = ws[0] + ws[1] + ws[2] + ws[3];
  sq = ws[4] + ws[5] + ws[6] + ws[7];
  float mean = s * (1.0f / 1024.0f);
  float var = sq * (1.0f / 1024.0f) - mean * mean;
  float rs = rsqrtf(var + 1e-5f);
  float4 gv = ((const float4*)g)[tid];
  float4 bv = ((const float4*)bt)[tid];
  float4 y;
  y.x = (v.x - mean) * rs * gv.x + bv.x;
  y.y = (v.y - mean) * rs * gv.y + bv.y;
  y.z = (v.z - mean) * rs * gv.z + bv.z;
  y.w = (v.w - mean) * rs * gv.w + bv.w;
  ((float4*)(sf + row * 1024))[tid] = y;
  u16x4 yb = { f2bf(y.x), f2bf(y.y), f2bf(y.z), f2bf(y.w) };
  ((u16x4*)(sb + row * 1024))[tid] = yb;
}

__global__ __launch_bounds__(256) void ln2_kernel(const float* __restrict__ skip,
                                                  const float* __restrict__ fcc,
                                                  const float* __restrict__ g,
                                                  const float* __restrict__ bt,
                                                  const float* __restrict__ x,
                                                  const float* __restrict__ alphap,
                                                  float* __restrict__ out) {
  const int row = blockIdx.x, tid = threadIdx.x;
  float4 sv = ((const float4*)(skip + row * 1024))[tid];
  float4 fv = ((const float4*)(fcc + row * 1024))[tid];
  float4 v = {sv.x + fv.x, sv.y + fv.y, sv.z + fv.z, sv.w + fv.w};
  float s = v.x + v.y + v.z + v.w;
  float sq = v.x * v.x + v.y * v.y + v.z * v.z + v.w * v.w;
#pragma unroll
  for (int off = 1; off < 64; off <<= 1) { s += __shfl_xor(s, off); sq += __shfl_xor(sq, off); }
  __shared__ float ws[8];
  int wv = tid >> 6, l = tid & 63;
  if (l == 0) { ws[wv] = s; ws[4 + wv] = sq; }
  __syncthreads();
  s = ws[0] + ws[1] + ws[2] + ws[3];
  sq = ws[4] + ws[5] + ws[6] + ws[7];
  float mean = s * (1.0f / 1024.0f);
  float var = sq * (1.0f / 1024.0f) - mean * mean;
  float rs = rsqrtf(var + 1e-5f);
  float4 gv = ((const float4*)g)[tid];
  float4 bv = ((const float4*)bt)[tid];
  float alpha = alphap[0];
  float beta = 1.0f - alpha;
  float4 xv = ((const float4*)(x + row * 1024))[tid];
  float4 y;
  y.x = xv.x * alpha + ((v.x - mean) * rs * gv.x + bv.x) * beta;
  y.y = xv.y * alpha + ((v.y - mean) * rs * gv.y + bv.y) * beta;
  y.z = xv.z * alpha + ((v.z - mean) * rs * gv.z + bv.z) * beta;
  y.w = xv.w * alpha + ((v.w - mean) * rs * gv.w + bv.w) * beta;
  ((float4*)(out + row * 1024))[tid] = y;
}

// ---------------- launch ----------------
extern "C" void kernel_launch(void* const* d_in, const int* in_sizes, int n_in,
                              void* d_out, int out_size, void* d_ws, size_t ws_size,
                              hipStream_t stream) {
  const float* x  = (const float*)d_in[0];
  const int* mask = (const int*)d_in[1];
  const float* Wq = (const float*)d_in[2];
  const float* bq = (const float*)d_in[3];
  const float* Wk = (const float*)d_in[4];
  const float* bk = (const float*)d_in[5];
  const float* Wv = (const float*)d_in[6];
  const float* bv = (const float*)d_in[7];
  const float* Wo = (const float*)d_in[8];
  const float* bo = (const float*)d_in[9];
  const float* g1 = (const float*)d_in[10];
  const float* b1 = (const float*)d_in[11];
  const float* Wf = (const float*)d_in[12];
  const float* bf = (const float*)d_in[13];
  const float* g2 = (const float*)d_in[14];
  const float* b2 = (const float*)d_in[15];
  const float* alpha = (const float*)d_in[16];
  float* out = (float*)d_out;

  char* ws = (char*)d_ws;
  size_t off = 0;
  unsigned short* xb   = (unsigned short*)(ws + off); off += 8388608;   // 4096x1024 bf16
  unsigned short* Wqkv = (unsigned short*)(ws + off); off += 6291456;   // 3072x1024 bf16
  unsigned short* Wob  = (unsigned short*)(ws + off); off += 2097152;
  unsigned short* Wfb  = (unsigned short*)(ws + off); off += 2097152;
  float* bcat          = (float*)(ws + off);          off += 12288;
  float* maf           = (float*)(ws + off);          off += 16384;     // maskadd [4][1024]
  unsigned short* qkvb = (unsigned short*)(ws + off); off += 25165824;  // 4096x3072 bf16
  unsigned short* attb = (unsigned short*)(ws + off); off += 8388608;
  float* tmp           = (float*)(ws + off);          off += 16777216;  // VT (attn) -> att@Wo -> fcc
  float* s1f           = (float*)(ws + off);          off += 16777216;
  unsigned short* s1b  = (unsigned short*)(ws + off); off += 8388608;

  unsigned short* VT = (unsigned short*)tmp;  // 8MB, used only during attention

  // casts + prep
  cast_f32_bf16<<<4096, 256, 0, stream>>>(x, xb, 1048576);
  cast_f32_bf16<<<1024, 256, 0, stream>>>(Wq, Wqkv, 262144);
  cast_f32_bf16<<<1024, 256, 0, stream>>>(Wk, Wqkv + 1048576, 262144);
  cast_f32_bf16<<<1024, 256, 0, stream>>>(Wv, Wqkv + 2097152, 262144);
  cast_f32_bf16<<<1024, 256, 0, stream>>>(Wo, Wob, 262144);
  cast_f32_bf16<<<1024, 256, 0, stream>>>(Wf, Wfb, 262144);
  maskadd_kernel<<<16, 256, 0, stream>>>(mask, maf);
  hipMemcpyAsync(bcat,        bq, 4096, hipMemcpyDeviceToDevice, stream);
  hipMemcpyAsync(bcat + 1024, bk, 4096, hipMemcpyDeviceToDevice, stream);
  hipMemcpyAsync(bcat + 2048, bv, 4096, hipMemcpyDeviceToDevice, stream);

  // fused QKV GEMM: [4096,1024] x [3072,1024]^T -> bf16 [4096,3072]
  gemm_lds<0><<<dim3(32, 24), 256, 0, stream>>>(xb, Wqkv, bcat, qkvb, 4096, 3072, 1024);

  // V transpose -> VT[(bh*64+d)][k]
  vtrans_kernel<<<dim3(64, 16), 256, 0, stream>>>(qkvb, VT);

  // attention -> att bf16 [4096,1024]
  attn3_kernel<<<dim3(64, 16), 256, 0, stream>>>(qkvb, VT, maf, attb);

  // O projection -> f32 tmp
  gemm_lds<1><<<dim3(32, 8), 256, 0, stream>>>(attb, Wob, bo, tmp, 4096, 1024, 1024);

  // LN1: skip1 = LN(x + tmp); emits f32 + bf16
  ln1_kernel<<<4096, 256, 0, stream>>>(x, tmp, g1, b1, s1f, s1b);

  // FF GEMM + exact GELU -> f32 (reuse tmp)
  gemm_lds<2><<<dim3(32, 8), 256, 0, stream>>>(s1b, Wfb, bf, tmp, 4096, 1024, 1024);

  // LN2 + final mix
  ln2_kernel<<<4096, 256, 0, stream>>>(s1f, tmp, g2, b2, x, alpha, out);
}

// Round 6
// 215.885 us; speedup vs baseline: 1.2917x; 1.2917x over previous
//
#include <hip/hip_runtime.h>

typedef __attribute__((ext_vector_type(8))) short short8;
typedef __attribute__((ext_vector_type(4))) float f32x4;
typedef __attribute__((ext_vector_type(4))) unsigned short u16x4;

#define MFMA_BF16(a, b, c) __builtin_amdgcn_mfma_f32_16x16x32_bf16((a), (b), (c), 0, 0, 0)

__device__ __forceinline__ unsigned short f2bf(float f) {
  unsigned int u = __builtin_bit_cast(unsigned int, f);
  u += 0x7fffu + ((u >> 16) & 1u);
  return (unsigned short)(u >> 16);
}

// async global->LDS, 16 bytes per lane; LDS dest = wave-uniform base + lane*16
__device__ __forceinline__ void gload_lds16(const void* g, void* lds) {
  __builtin_amdgcn_global_load_lds(
      (const __attribute__((address_space(1))) unsigned int*)g,
      (__attribute__((address_space(3))) unsigned int*)lds, 16, 0, 0);
}

// ---------------- cast f32 -> bf16 (vectorized) ----------------
__global__ __launch_bounds__(256) void cast_f32_bf16(const float* __restrict__ src,
                                                     unsigned short* __restrict__ dst, int n4) {
  int i = blockIdx.x * 256 + threadIdx.x;
  if (i >= n4) return;
  float4 v = ((const float4*)src)[i];
  u16x4 r = { f2bf(v.x), f2bf(v.y), f2bf(v.z), f2bf(v.w) };
  ((u16x4*)dst)[i] = r;
}

// ---------------- GEMM (m97 structure): C[M,N] = A[M,K] * W[N,K]^T + bias ----------------
template <int EPI>
__global__ __launch_bounds__(256) void gemm_lds(const unsigned short* __restrict__ A,
                                                const unsigned short* __restrict__ W,
                                                const float* __restrict__ bias,
                                                void* __restrict__ Cout,
                                                int M, int N, int K) {
  __shared__ unsigned short At[128 * 32];
  __shared__ unsigned short Bt[128 * 32];

  const int tid = threadIdx.x;
  const int w = tid >> 6, l = tid & 63;
  const int lr = l & 15, lq = l >> 4;
  const int wr = w >> 1, wc = w & 1;
  const int row0 = blockIdx.x * 128;
  const int col0 = blockIdx.y * 128;

  const int srow = l >> 2;
  const int skoff = (l & 3) * 8;

  f32x4 acc[4][4] = {};

  const unsigned short* Abase = A + (row0 + srow) * (size_t)K + skoff;
  const unsigned short* Bbase = W + (col0 + srow) * (size_t)K + skoff;

  for (int kt = 0; kt < K; kt += 32) {
#pragma unroll
    for (int j = 0; j < 2; j++) {
      const int c = w * 2 + j;
      gload_lds16(Abase + (size_t)(c * 16) * K + kt, &At[c * 512]);
      gload_lds16(Bbase + (size_t)(c * 16) * K + kt, &Bt[c * 512]);
    }
    __syncthreads();

    short8 af[4], bfr[4];
#pragma unroll
    for (int m = 0; m < 4; m++)
      af[m] = *(const short8*)&At[(wr * 64 + m * 16 + lr) * 32 + lq * 8];
#pragma unroll
    for (int n = 0; n < 4; n++)
      bfr[n] = *(const short8*)&Bt[(wc * 64 + n * 16 + lr) * 32 + lq * 8];
#pragma unroll
    for (int m = 0; m < 4; m++)
#pragma unroll
      for (int n = 0; n < 4; n++)
        acc[m][n] = MFMA_BF16(af[m], bfr[n], acc[m][n]);
    __syncthreads();
  }

#pragma unroll
  for (int n = 0; n < 4; n++) {
    const int col = col0 + wc * 64 + n * 16 + lr;
    const float bv = bias[col];
#pragma unroll
    for (int m = 0; m < 4; m++) {
      const int row = row0 + wr * 64 + m * 16 + lq * 4;
#pragma unroll
      for (int r = 0; r < 4; r++) {
        float v = acc[m][n][r] + bv;
        if (EPI == 0) {
          ((unsigned short*)Cout)[(size_t)(row + r) * N + col] = f2bf(v);
        } else if (EPI == 1) {
          ((float*)Cout)[(size_t)(row + r) * N + col] = v;
        } else {
          float g = 0.5f * v * (1.0f + erff(v * 0.70710678118654752f));
          ((float*)Cout)[(size_t)(row + r) * N + col] = g;
        }
      }
    }
  }
}

// ---------------- maskadd (log2 domain): ma[b][k] = mask ? 0 : -1e10*log2e ----------------
__global__ __launch_bounds__(256) void maskadd_kernel(const int* __restrict__ mask,
                                                      float* __restrict__ ma) {
  int i = blockIdx.x * 256 + threadIdx.x;
  if (i < 4096) ma[i] = (mask[i] == 0) ? -1.4426950408889634e10f : 0.0f;
}

// ---------------- V transpose: VT[(bh*64+d)][k] <- v-slab of qkv ----------------
__global__ __launch_bounds__(256) void vtrans_kernel(const unsigned short* __restrict__ qkv,
                                                     unsigned short* __restrict__ VT) {
  const int bh = blockIdx.x;   // 64
  const int kt = blockIdx.y;   // 16 tiles of 64 keys
  const int t = threadIdx.x;
  const int d = t & 63, kg = t >> 6;
  const unsigned short* basev =
      qkv + ((size_t)(bh >> 4) * 1024 + (bh & 15) * 64) * 3072 + 2048;
  const unsigned short* src = basev + (size_t)(kt * 4 + kg) * 3072 + d;
  unsigned short vals[16];
#pragma unroll
  for (int j = 0; j < 16; j++) vals[j] = src[j * 64];
  short8 v0, v1;
#pragma unroll
  for (int j = 0; j < 8; j++) { v0[j] = (short)vals[j]; v1[j] = (short)vals[8 + j]; }
  size_t dst = ((size_t)bh * 64 + d) * 1024 + kt * 64 + kg * 16;
  *(short8*)&VT[dst] = v0;
  *(short8*)&VT[dst + 8] = v1;
}

// ---------------- flash attention v4 ----------------
// attn2 structure (32 q/wave, 16 MFMA per KV load) + 2-tile-deep prefetch
// + exp2-domain softmax with LDS-staged scaled mask.
struct KV {
  short8 kf[2][2];   // [key-half][d-chunk]
  short8 vf[4];      // V^T frags per d-tile
};

__device__ __forceinline__ void load_kv(KV& f, int kt,
                                        const unsigned short* __restrict__ basek,
                                        const unsigned short* __restrict__ vtb,
                                        int lr, int lq) {
#pragma unroll
  for (int t = 0; t < 2; t++) {
    const unsigned short* ka = basek + (size_t)(kt * 2 + t) * 3072 + lr * 64;
    f.kf[t][0] = *(const short8*)(ka + lq * 8);
    f.kf[t][1] = *(const short8*)(ka + 32 + lq * 8);
  }
#pragma unroll
  for (int n = 0; n < 4; n++)
    f.vf[n] = *(const short8*)(vtb + (size_t)(n * 16 + lr) * 1024 + kt * 32 + lq * 8);
}

__device__ __forceinline__ void process(const KV& f, int kcur, const short8 qf[2][2],
                                        const float* __restrict__ ma_lds,
                                        unsigned short* pw0, unsigned short* pw1,
                                        float m[2], float ll[2], f32x4 o[2][4],
                                        int lr, int lq) {
  constexpr float SC = 0.18033688011112042f;  // 0.125 * log2(e)
  unsigned short* pws[2] = {pw0, pw1};
  const float4 mk0 = *(const float4*)&ma_lds[kcur * 32 + lq * 4];
  const float4 mk1 = *(const float4*)&ma_lds[kcur * 32 + 16 + lq * 4];
#pragma unroll
  for (int qt2 = 0; qt2 < 2; qt2++) {
    // S^T tiles: rows = keys (lq*4+r [+16]), cols = q (lr)
    f32x4 s0 = {0.f, 0.f, 0.f, 0.f}, s1 = {0.f, 0.f, 0.f, 0.f};
    s0 = MFMA_BF16(f.kf[0][0], qf[qt2][0], s0);
    s0 = MFMA_BF16(f.kf[0][1], qf[qt2][1], s0);
    s1 = MFMA_BF16(f.kf[1][0], qf[qt2][0], s1);
    s1 = MFMA_BF16(f.kf[1][1], qf[qt2][1], s1);
    float sv[8];
#pragma unroll
    for (int r = 0; r < 4; r++) {
      sv[r]     = s0[r] * SC + ((const float*)&mk0)[r];
      sv[4 + r] = s1[r] * SC + ((const float*)&mk1)[r];
    }
    // online softmax (exp2 domain): state lane-local for q = lr; reduce over lq group
    float t = fmaxf(fmaxf(fmaxf(sv[0], sv[1]), fmaxf(sv[2], sv[3])),
                    fmaxf(fmaxf(sv[4], sv[5]), fmaxf(sv[6], sv[7])));
    t = fmaxf(t, __shfl_xor(t, 16));
    t = fmaxf(t, __shfl_xor(t, 32));
    float mn = fmaxf(m[qt2], t);
    float sc = __builtin_amdgcn_exp2f(m[qt2] - mn);
    m[qt2] = mn;
    float p[8], rs = 0.f;
#pragma unroll
    for (int i = 0; i < 8; i++) { p[i] = __builtin_amdgcn_exp2f(sv[i] - mn); rs += p[i]; }
    rs += __shfl_xor(rs, 16);
    rs += __shfl_xor(rs, 32);
    ll[qt2] = ll[qt2] * sc + rs;
    // pack P (bf16) to per-wave LDS: P[q=lr][k_local], stride 40
    uint2 wa, wb;
    wa.x = (unsigned)f2bf(p[0]) | ((unsigned)f2bf(p[1]) << 16);
    wa.y = (unsigned)f2bf(p[2]) | ((unsigned)f2bf(p[3]) << 16);
    wb.x = (unsigned)f2bf(p[4]) | ((unsigned)f2bf(p[5]) << 16);
    wb.y = (unsigned)f2bf(p[6]) | ((unsigned)f2bf(p[7]) << 16);
    *(uint2*)&pws[qt2][lr * 40 + lq * 4] = wa;
    *(uint2*)&pws[qt2][lr * 40 + 16 + lq * 4] = wb;
    // rescale O (rows q = lq*4+r use sc of lane lq*4+r)
    float scr[4];
#pragma unroll
    for (int r = 0; r < 4; r++) scr[r] = __shfl(sc, lq * 4 + r);
#pragma unroll
    for (int n = 0; n < 4; n++)
#pragma unroll
      for (int r = 0; r < 4; r++) o[qt2][n][r] *= scr[r];
  }
  asm volatile("s_waitcnt lgkmcnt(0)" ::: "memory");
  // PV: A = P[q=lr][k=lq*8..+7] (b128 from LDS), B = V^T frags
#pragma unroll
  for (int qt2 = 0; qt2 < 2; qt2++) {
    const short8 pa = *(const short8*)&pws[qt2][lr * 40 + lq * 8];
#pragma unroll
    for (int n = 0; n < 4; n++)
      o[qt2][n] = MFMA_BF16(pa, f.vf[n], o[qt2][n]);
  }
}

__global__ __launch_bounds__(256) void attn4_kernel(const unsigned short* __restrict__ qkv,
                                                    const unsigned short* __restrict__ VT,
                                                    const float* __restrict__ maskadd,
                                                    unsigned short* __restrict__ att) {
  __shared__ float ma_lds[1024];
  __shared__ unsigned short Pl[4][2][640];  // per wave, per q-tile: [16 q][40]

  const int bh = blockIdx.x, b = bh >> 4, h = bh & 15;
  const int qb = blockIdx.y;
  const int tid = threadIdx.x, w = tid >> 6, l = tid & 63;
  const int lr = l & 15, lq = l >> 4;

  const unsigned short* baseq = qkv + ((size_t)b * 1024 + h * 64) * 3072;
  const unsigned short* basek = baseq + 1024;
  const unsigned short* vtb = VT + (size_t)bh * 64 * 1024;

  // stage scaled mask row into LDS once
  ((float4*)ma_lds)[tid] = ((const float4*)(maskadd + b * 1024))[tid];
  __syncthreads();

  // Q fragments (2 tiles x 2 d-chunks), resident all kernel
  short8 qf[2][2];
  const int q0 = qb * 128 + w * 32;
#pragma unroll
  for (int t = 0; t < 2; t++) {
    int p = q0 + t * 16 + lr;
    const unsigned short* qa = baseq + (p >> 4) * 3072 + (p & 15) * 64;
    qf[t][0] = *(const short8*)(qa + lq * 8);
    qf[t][1] = *(const short8*)(qa + 32 + lq * 8);
  }

  float m[2] = {-1e30f, -1e30f}, ll[2] = {0.f, 0.f};
  f32x4 o[2][4] = {};

  unsigned short* pw0 = &Pl[w][0][0];
  unsigned short* pw1 = &Pl[w][1][0];

  // 3-buffer rotation, 2 tiles of lookahead
  KV f0, f1, f2;
  load_kv(f0, 0, basek, vtb, lr, lq);
  load_kv(f1, 1, basek, vtb, lr, lq);
#pragma unroll 1
  for (int kt = 0; kt < 30; kt += 3) {
    load_kv(f2, kt + 2, basek, vtb, lr, lq);
    process(f0, kt, qf, ma_lds, pw0, pw1, m, ll, o, lr, lq);
    load_kv(f0, kt + 3, basek, vtb, lr, lq);
    process(f1, kt + 1, qf, ma_lds, pw0, pw1, m, ll, o, lr, lq);
    load_kv(f1, kt + 4, basek, vtb, lr, lq);
    process(f2, kt + 2, qf, ma_lds, pw0, pw1, m, ll, o, lr, lq);
  }
  process(f0, 30, qf, ma_lds, pw0, pw1, m, ll, o, lr, lq);
  process(f1, 31, qf, ma_lds, pw0, pw1, m, ll, o, lr, lq);

  // epilogue: normalize, write att[b, q, h*64 + d]
#pragma unroll
  for (int qt2 = 0; qt2 < 2; qt2++) {
    float inv[4];
#pragma unroll
    for (int r = 0; r < 4; r++) inv[r] = 1.0f / __shfl(ll[qt2], lq * 4 + r);
#pragma unroll
    for (int r = 0; r < 4; r++) {
      int q = q0 + qt2 * 16 + lq * 4 + r;
      size_t obase = ((size_t)b * 1024 + q) * 1024 + h * 64;
#pragma unroll
      for (int n = 0; n < 4; n++)
        att[obase + n * 16 + lr] = f2bf(o[qt2][n][r] * inv[r]);
    }
  }
}

// ---------------- LayerNorm kernels (fp32, E=1024, one row per block) ----------------
__global__ __launch_bounds__(256) void ln1_kernel(const float* __restrict__ x,
                                                  const float* __restrict__ attp,
                                                  const float* __restrict__ g,
                                                  const float* __restrict__ bt,
                                                  float* __restrict__ sf,
                                                  unsigned short* __restrict__ sb) {
  const int row = blockIdx.x, tid = threadIdx.x;
  float4 xv = ((const float4*)(x + row * 1024))[tid];
  float4 av = ((const float4*)(attp + row * 1024))[tid];
  float4 v = {xv.x + av.x, xv.y + av.y, xv.z + av.z, xv.w + av.w};
  float s = v.x + v.y + v.z + v.w;
  float sq = v.x * v.x + v.y * v.y + v.z * v.z + v.w * v.w;
#pragma unroll
  for (int off = 1; off < 64; off <<= 1) { s += __shfl_xor(s, off); sq += __shfl_xor(sq, off); }
  __shared__ float ws[8];
  int wv = tid >> 6, l = tid & 63;
  if (l == 0) { ws[wv] = s; ws[4 + wv] = sq; }
  __syncthreads();
  s = ws[0] + ws[1] + ws[2] + ws[3];
  sq = ws[4] + ws[5] + ws[6] + ws[7];
  float mean = s * (1.0f / 1024.0f);
  float var = sq * (1.0f / 1024.0f) - mean * mean;
  float rs = rsqrtf(var + 1e-5f);
  float4 gv = ((const float4*)g)[tid];
  float4 bv = ((const float4*)bt)[tid];
  float4 y;
  y.x = (v.x - mean) * rs * gv.x + bv.x;
  y.y = (v.y - mean) * rs * gv.y + bv.y;
  y.z = (v.z - mean) * rs * gv.z + bv.z;
  y.w = (v.w - mean) * rs * gv.w + bv.w;
  ((float4*)(sf + row * 1024))[tid] = y;
  u16x4 yb = { f2bf(y.x), f2bf(y.y), f2bf(y.z), f2bf(y.w) };
  ((u16x4*)(sb + row * 1024))[tid] = yb;
}

__global__ __launch_bounds__(256) void ln2_kernel(const float* __restrict__ skip,
                                                  const float* __restrict__ fcc,
                                                  const float* __restrict__ g,
                                                  const float* __restrict__ bt,
                                                  const float* __restrict__ x,
                                                  const float* __restrict__ alphap,
                                                  float* __restrict__ out) {
  const int row = blockIdx.x, tid = threadIdx.x;
  float4 sv = ((const float4*)(skip + row * 1024))[tid];
  float4 fv = ((const float4*)(fcc + row * 1024))[tid];
  float4 v = {sv.x + fv.x, sv.y + fv.y, sv.z + fv.z, sv.w + fv.w};
  float s = v.x + v.y + v.z + v.w;
  float sq = v.x * v.x + v.y * v.y + v.z * v.z + v.w * v.w;
#pragma unroll
  for (int off = 1; off < 64; off <<= 1) { s += __shfl_xor(s, off); sq += __shfl_xor(sq, off); }
  __shared__ float ws[8];
  int wv = tid >> 6, l = tid & 63;
  if (l == 0) { ws[wv] = s; ws[4 + wv] = sq; }
  __syncthreads();
  s = ws[0] + ws[1] + ws[2] + ws[3];
  sq = ws[4] + ws[5] + ws[6] + ws[7];
  float mean = s * (1.0f / 1024.0f);
  float var = sq * (1.0f / 1024.0f) - mean * mean;
  float rs = rsqrtf(var + 1e-5f);
  float4 gv = ((const float4*)g)[tid];
  float4 bv = ((const float4*)bt)[tid];
  float alpha = alphap[0];
  float beta = 1.0f - alpha;
  float4 xv = ((const float4*)(x + row * 1024))[tid];
  float4 y;
  y.x = xv.x * alpha + ((v.x - mean) * rs * gv.x + bv.x) * beta;
  y.y = xv.y * alpha + ((v.y - mean) * rs * gv.y + bv.y) * beta;
  y.z = xv.z * alpha + ((v.z - mean) * rs * gv.z + bv.z) * beta;
  y.w = xv.w * alpha + ((v.w - mean) * rs * gv.w + bv.w) * beta;
  ((float4*)(out + row * 1024))[tid] = y;
}

// ---------------- launch ----------------
extern "C" void kernel_launch(void* const* d_in, const int* in_sizes, int n_in,
                              void* d_out, int out_size, void* d_ws, size_t ws_size,
                              hipStream_t stream) {
  const float* x  = (const float*)d_in[0];
  const int* mask = (const int*)d_in[1];
  const float* Wq = (const float*)d_in[2];
  const float* bq = (const float*)d_in[3];
  const float* Wk = (const float*)d_in[4];
  const float* bk = (const float*)d_in[5];
  const float* Wv = (const float*)d_in[6];
  const float* bv = (const float*)d_in[7];
  const float* Wo = (const float*)d_in[8];
  const float* bo = (const float*)d_in[9];
  const float* g1 = (const float*)d_in[10];
  const float* b1 = (const float*)d_in[11];
  const float* Wf = (const float*)d_in[12];
  const float* bf = (const float*)d_in[13];
  const float* g2 = (const float*)d_in[14];
  const float* b2 = (const float*)d_in[15];
  const float* alpha = (const float*)d_in[16];
  float* out = (float*)d_out;

  char* ws = (char*)d_ws;
  size_t off = 0;
  unsigned short* xb   = (unsigned short*)(ws + off); off += 8388608;   // 4096x1024 bf16
  unsigned short* Wqkv = (unsigned short*)(ws + off); off += 6291456;   // 3072x1024 bf16
  unsigned short* Wob  = (unsigned short*)(ws + off); off += 2097152;
  unsigned short* Wfb  = (unsigned short*)(ws + off); off += 2097152;
  float* bcat          = (float*)(ws + off);          off += 12288;
  float* maf           = (float*)(ws + off);          off += 16384;     // maskadd [4][1024]
  unsigned short* qkvb = (unsigned short*)(ws + off); off += 25165824;  // 4096x3072 bf16
  unsigned short* attb = (unsigned short*)(ws + off); off += 8388608;
  float* tmp           = (float*)(ws + off);          off += 16777216;  // VT (attn) -> att@Wo -> fcc
  float* s1f           = (float*)(ws + off);          off += 16777216;
  unsigned short* s1b  = (unsigned short*)(ws + off); off += 8388608;

  unsigned short* VT = (unsigned short*)tmp;  // 8MB, used only during attention

  // casts + prep
  cast_f32_bf16<<<4096, 256, 0, stream>>>(x, xb, 1048576);
  cast_f32_bf16<<<1024, 256, 0, stream>>>(Wq, Wqkv, 262144);
  cast_f32_bf16<<<1024, 256, 0, stream>>>(Wk, Wqkv + 1048576, 262144);
  cast_f32_bf16<<<1024, 256, 0, stream>>>(Wv, Wqkv + 2097152, 262144);
  cast_f32_bf16<<<1024, 256, 0, stream>>>(Wo, Wob, 262144);
  cast_f32_bf16<<<1024, 256, 0, stream>>>(Wf, Wfb, 262144);
  maskadd_kernel<<<16, 256, 0, stream>>>(mask, maf);
  hipMemcpyAsync(bcat,        bq, 4096, hipMemcpyDeviceToDevice, stream);
  hipMemcpyAsync(bcat + 1024, bk, 4096, hipMemcpyDeviceToDevice, stream);
  hipMemcpyAsync(bcat + 2048, bv, 4096, hipMemcpyDeviceToDevice, stream);

  // fused QKV GEMM: [4096,1024] x [3072,1024]^T -> bf16 [4096,3072]
  gemm_lds<0><<<dim3(32, 24), 256, 0, stream>>>(xb, Wqkv, bcat, qkvb, 4096, 3072, 1024);

  // V transpose -> VT[(bh*64+d)][k]
  vtrans_kernel<<<dim3(64, 16), 256, 0, stream>>>(qkvb, VT);

  // attention -> att bf16 [4096,1024]
  attn4_kernel<<<dim3(64, 8), 256, 0, stream>>>(qkvb, VT, maf, attb);

  // O projection -> f32 tmp
  gemm_lds<1><<<dim3(32, 8), 256, 0, stream>>>(attb, Wob, bo, tmp, 4096, 1024, 1024);

  // LN1: skip1 = LN(x + tmp); emits f32 + bf16
  ln1_kernel<<<4096, 256, 0, stream>>>(x, tmp, g1, b1, s1f, s1b);

  // FF GEMM + exact GELU -> f32 (reuse tmp)
  gemm_lds<2><<<dim3(32, 8), 256, 0, stream>>>(s1b, Wfb, bf, tmp, 4096, 1024, 1024);

  // LN2 + final mix
  ln2_kernel<<<4096, 256, 0, stream>>>(s1f, tmp, g2, b2, x, alpha, out);
}